// Round 1
// baseline (287.071 us; speedup 1.0000x reference)
//
#include <hip/hip_runtime.h>

#define T_LEN  16384
#define CHUNK  64
#define NTHR   256   // chunks per row

// Causal unbiased-EMA instance norm, one block per (b,c) row.
// Thread j owns t in [64j, 64j+64). Two-pass: local scan -> block scan of
// affine carries (decay alpha^64 per chunk) -> recompute + normalize.
__global__ __launch_bounds__(NTHR, 2)
void ema_norm_kernel(const float* __restrict__ x, float* __restrict__ y) {
    const float A    = 0.99f;                     // fl32(0.99)
    const float OMA  = (float)(1.0 - 0.99);       // fl32(0.01) = 0.0099999997765
    const float EPSF = 1e-5f;
    // fixed point of the fp32 reference recurrence w = A*w + OMA
    const float Kf = (float)((double)((float)(1.0 - 0.99)) / (1.0 - (double)0.99f));

    const int row  = blockIdx.x;
    const int tid  = threadIdx.x;
    const int lane = tid & 63;
    const int wid  = tid >> 6;

    const float4* __restrict__ xr =
        reinterpret_cast<const float4*>(x + (size_t)row * T_LEN + (size_t)tid * CHUNK);
    float4* __restrict__ yr =
        reinterpret_cast<float4*>(y + (size_t)row * T_LEN + (size_t)tid * CHUNK);

    // ---- load 64 elements (16 x float4), keep in registers ----
    float4 xv[16];
#pragma unroll
    for (int i = 0; i < 16; ++i) xv[i] = xr[i];

    // ---- pass 1: local EMA scan from zero carry ----
    float s1 = 0.f, s2 = 0.f;
#pragma unroll
    for (int i = 0; i < 16; ++i) {
        float t;
        t = OMA * xv[i].x; s1 = fmaf(A, s1, t); s2 = fmaf(A, s2, t * xv[i].x);
        t = OMA * xv[i].y; s1 = fmaf(A, s1, t); s2 = fmaf(A, s2, t * xv[i].y);
        t = OMA * xv[i].z; s1 = fmaf(A, s1, t); s2 = fmaf(A, s2, t * xv[i].z);
        t = OMA * xv[i].w; s1 = fmaf(A, s1, t); s2 = fmaf(A, s2, t * xv[i].w);
    }

    // decay constants: d[k] = alpha^(64 * 2^k), exact repeated squaring
    float a64 = A;
#pragma unroll
    for (int i = 0; i < 6; ++i) a64 *= a64;       // alpha^64
    float d[8];
    d[0] = a64;
#pragma unroll
    for (int k = 1; k < 8; ++k) d[k] = d[k - 1] * d[k - 1];

    // ---- wave-level inclusive scan (Hillis-Steele with decay) ----
    float v1 = s1, v2 = s2;
#pragma unroll
    for (int k = 0; k < 6; ++k) {
        const int off = 1 << k;
        float o1 = __shfl_up(v1, off, 64);
        float o2 = __shfl_up(v2, off, 64);
        if (lane >= off) { v1 = fmaf(d[k], o1, v1); v2 = fmaf(d[k], o2, v2); }
    }
    // exclusive carry within wave
    float c1 = __shfl_up(v1, 1, 64);
    float c2 = __shfl_up(v2, 1, 64);
    if (lane == 0) { c1 = 0.f; c2 = 0.f; }

    // ---- cross-wave scan of wave totals ----
    __shared__ float tot1[4], tot2[4];
    if (lane == 63) { tot1[wid] = v1; tot2[wid] = v2; }
    __syncthreads();
    float W1 = 0.f, W2 = 0.f;
    const float Dw = d[6];                        // alpha^4096 (per-wave decay)
    for (int v = 0; v < wid; ++v) {
        W1 = fmaf(W1, Dw, tot1[v]);
        W2 = fmaf(W2, Dw, tot2[v]);
    }
    // decay of wave carry to this lane's chunk start: alpha^(64*lane)
    float fdec = 1.f;
#pragma unroll
    for (int k = 0; k < 6; ++k) if (lane & (1 << k)) fdec *= d[k];
    c1 = fmaf(W1, fdec, c1);
    c2 = fmaf(W2, fdec, c2);

    // ---- starting bias weight: w0 = K*(1 - alpha^(64*tid)); tid 0 exact ref path ----
    float pw = 1.f;
#pragma unroll
    for (int k = 0; k < 8; ++k) if (tid & (1 << k)) pw *= d[k];
    float wrun = (tid == 0) ? 0.f : Kf * (1.f - pw);

    // ---- pass 2: recompute with carry, normalize, store ----
    s1 = c1; s2 = c2;
#pragma unroll
    for (int i = 0; i < 16; ++i) {
        float4 xq = xv[i];
        float4 oq;
        {   float xi = xq.x; float t = OMA * xi;
            s1 = fmaf(A, s1, t); s2 = fmaf(A, s2, t * xi);
            wrun = fmaf(A, wrun, OMA);
            float invw = 1.0f / wrun;
            float mean = s1 * invw;
            float var  = fmaf(-mean, mean, s2 * invw);
            float rs   = __builtin_amdgcn_rsqf(var + EPSF);
            oq.x = (xi - mean) * rs; }
        {   float xi = xq.y; float t = OMA * xi;
            s1 = fmaf(A, s1, t); s2 = fmaf(A, s2, t * xi);
            wrun = fmaf(A, wrun, OMA);
            float invw = 1.0f / wrun;
            float mean = s1 * invw;
            float var  = fmaf(-mean, mean, s2 * invw);
            float rs   = __builtin_amdgcn_rsqf(var + EPSF);
            oq.y = (xi - mean) * rs; }
        {   float xi = xq.z; float t = OMA * xi;
            s1 = fmaf(A, s1, t); s2 = fmaf(A, s2, t * xi);
            wrun = fmaf(A, wrun, OMA);
            float invw = 1.0f / wrun;
            float mean = s1 * invw;
            float var  = fmaf(-mean, mean, s2 * invw);
            float rs   = __builtin_amdgcn_rsqf(var + EPSF);
            oq.z = (xi - mean) * rs; }
        {   float xi = xq.w; float t = OMA * xi;
            s1 = fmaf(A, s1, t); s2 = fmaf(A, s2, t * xi);
            wrun = fmaf(A, wrun, OMA);
            float invw = 1.0f / wrun;
            float mean = s1 * invw;
            float var  = fmaf(-mean, mean, s2 * invw);
            float rs   = __builtin_amdgcn_rsqf(var + EPSF);
            oq.w = (xi - mean) * rs; }
        yr[i] = oq;
    }
}

extern "C" void kernel_launch(void* const* d_in, const int* in_sizes, int n_in,
                              void* d_out, int out_size, void* d_ws, size_t ws_size,
                              hipStream_t stream) {
    const float* x = (const float*)d_in[0];
    float* y = (float*)d_out;
    const int rows = in_sizes[0] / T_LEN;   // B*C = 2048
    ema_norm_kernel<<<rows, NTHR, 0, stream>>>(x, y);
}

// Round 3
// 239.327 us; speedup vs baseline: 1.1995x; 1.1995x over previous
//
#include <hip/hip_runtime.h>

#define T_LEN  16384
#define CHUNK  16              // elements per thread (4 x float4)
#define NTHR   1024            // one row per 1024-thread block
#define NWAVE  (NTHR / 64)

// Causal unbiased-EMA instance norm, one block per (b,c) row.
// Thread j owns t in [16j, 16j+16). Lane stride 64B -> coalesced ld/st.
// Two-pass: local scan -> wave scan (decay a^(16*2^k)) -> 16-wave LDS scan
// (decay a^1024) -> recompute + normalize from carried state.
__global__ __launch_bounds__(NTHR, 2)
void ema_norm_kernel(const float* __restrict__ x, float* __restrict__ y) {
    const float A    = 0.99f;                     // fl32(0.99)
    const float OMA  = (float)(1.0 - 0.99);       // fl32(0.01)
    const float EPSF = 1e-5f;
    // fixed point of the fp32 reference recurrence w = A*w + OMA
    const float Kf = (float)((double)((float)(1.0 - 0.99)) / (1.0 - (double)0.99f));

    const int row  = blockIdx.x;
    const int tid  = threadIdx.x;
    const int lane = tid & 63;
    const int wid  = tid >> 6;

    const float4* __restrict__ xr =
        reinterpret_cast<const float4*>(x + (size_t)row * T_LEN + (size_t)tid * CHUNK);
    float4* __restrict__ yr =
        reinterpret_cast<float4*>(y + (size_t)row * T_LEN + (size_t)tid * CHUNK);

    // ---- load 16 elements (4 x float4), keep in registers ----
    float4 xv[4];
#pragma unroll
    for (int i = 0; i < 4; ++i) xv[i] = xr[i];

    // ---- pass 1: local EMA scan from zero carry ----
    float s1 = 0.f, s2 = 0.f;
#pragma unroll
    for (int i = 0; i < 4; ++i) {
        float t;
        t = OMA * xv[i].x; s1 = fmaf(A, s1, t); s2 = fmaf(A, s2, t * xv[i].x);
        t = OMA * xv[i].y; s1 = fmaf(A, s1, t); s2 = fmaf(A, s2, t * xv[i].y);
        t = OMA * xv[i].z; s1 = fmaf(A, s1, t); s2 = fmaf(A, s2, t * xv[i].z);
        t = OMA * xv[i].w; s1 = fmaf(A, s1, t); s2 = fmaf(A, s2, t * xv[i].w);
    }

    // decay constants: d[k] = alpha^(16 * 2^k) by exact repeated squaring
    float a16 = A;
#pragma unroll
    for (int i = 0; i < 4; ++i) a16 *= a16;       // alpha^16
    float d[10];
    d[0] = a16;
#pragma unroll
    for (int k = 1; k < 10; ++k) d[k] = d[k - 1] * d[k - 1];

    // ---- wave-level inclusive scan (Hillis-Steele with decay) ----
    float v1 = s1, v2 = s2;
#pragma unroll
    for (int k = 0; k < 6; ++k) {
        const int off = 1 << k;
        float o1 = __shfl_up(v1, off, 64);
        float o2 = __shfl_up(v2, off, 64);
        if (lane >= off) { v1 = fmaf(d[k], o1, v1); v2 = fmaf(d[k], o2, v2); }
    }
    // exclusive carry within wave
    float c1 = __shfl_up(v1, 1, 64);
    float c2 = __shfl_up(v2, 1, 64);
    if (lane == 0) { c1 = 0.f; c2 = 0.f; }

    // ---- cross-wave scan of wave totals (16 waves, decay alpha^1024) ----
    __shared__ float tot1[NWAVE], tot2[NWAVE];
    if (lane == 63) { tot1[wid] = v1; tot2[wid] = v2; }
    __syncthreads();
    float W1 = 0.f, W2 = 0.f;
    const float Dw = d[6];                        // alpha^1024
    for (int v = 0; v < wid; ++v) {
        W1 = fmaf(W1, Dw, tot1[v]);
        W2 = fmaf(W2, Dw, tot2[v]);
    }
    // decay of wave carry to this lane's chunk start: alpha^(16*lane)
    float fdec = 1.f;
#pragma unroll
    for (int k = 0; k < 6; ++k) if (lane & (1 << k)) fdec *= d[k];
    c1 = fmaf(W1, fdec, c1);
    c2 = fmaf(W2, fdec, c2);

    // ---- starting bias weight: w0 = K*(1 - alpha^(16*tid)); tid 0 exact ref path ----
    float pw = 1.f;
#pragma unroll
    for (int k = 0; k < 10; ++k) if (tid & (1 << k)) pw *= d[k];
    float wrun = (tid == 0) ? 0.f : Kf * (1.f - pw);

    // ---- pass 2: recompute with carry, normalize, store ----
    s1 = c1; s2 = c2;
#pragma unroll
    for (int i = 0; i < 4; ++i) {
        float4 xq = xv[i];
        float4 oq;
        {   float xi = xq.x; float t = OMA * xi;
            s1 = fmaf(A, s1, t); s2 = fmaf(A, s2, t * xi);
            wrun = fmaf(A, wrun, OMA);
            float invw = 1.0f / wrun;
            float mean = s1 * invw;
            float var  = fmaf(-mean, mean, s2 * invw);
            float rs   = __builtin_amdgcn_rsqf(var + EPSF);
            oq.x = (xi - mean) * rs; }
        {   float xi = xq.y; float t = OMA * xi;
            s1 = fmaf(A, s1, t); s2 = fmaf(A, s2, t * xi);
            wrun = fmaf(A, wrun, OMA);
            float invw = 1.0f / wrun;
            float mean = s1 * invw;
            float var  = fmaf(-mean, mean, s2 * invw);
            float rs   = __builtin_amdgcn_rsqf(var + EPSF);
            oq.y = (xi - mean) * rs; }
        {   float xi = xq.z; float t = OMA * xi;
            s1 = fmaf(A, s1, t); s2 = fmaf(A, s2, t * xi);
            wrun = fmaf(A, wrun, OMA);
            float invw = 1.0f / wrun;
            float mean = s1 * invw;
            float var  = fmaf(-mean, mean, s2 * invw);
            float rs   = __builtin_amdgcn_rsqf(var + EPSF);
            oq.z = (xi - mean) * rs; }
        {   float xi = xq.w; float t = OMA * xi;
            s1 = fmaf(A, s1, t); s2 = fmaf(A, s2, t * xi);
            wrun = fmaf(A, wrun, OMA);
            float invw = 1.0f / wrun;
            float mean = s1 * invw;
            float var  = fmaf(-mean, mean, s2 * invw);
            float rs   = __builtin_amdgcn_rsqf(var + EPSF);
            oq.w = (xi - mean) * rs; }
        yr[i] = oq;
    }
}

extern "C" void kernel_launch(void* const* d_in, const int* in_sizes, int n_in,
                              void* d_out, int out_size, void* d_ws, size_t ws_size,
                              hipStream_t stream) {
    const float* x = (const float*)d_in[0];
    float* y = (float*)d_out;
    const int rows = in_sizes[0] / T_LEN;   // B*C = 2048
    ema_norm_kernel<<<rows, NTHR, 0, stream>>>(x, y);
}